// Round 1
// 529.582 us; speedup vs baseline: 1.1650x; 1.1650x over previous
//
#include <hip/hip_runtime.h>

#define EPS 1e-8f

constexpr int B = 16, C = 19, H = 512, W = 512;
constexpr int HW = H * W;               // 262144 = 2^18
constexpr int NPIX = B * HW;            // 4194304
constexpr long long NPRED = (long long)B * C * HW;  // 79691776

// ws layout (floats): [0..360] ncm (row-major [c][t]), [361..721] log(ncm+eps), [768] loss accumulator

__global__ void ncm_kernel(const float* __restrict__ cm, float* __restrict__ ws) {
    int t = threadIdx.x;
    if (t == 0) ws[768] = 0.0f;  // zero the loss accumulator (ws is poisoned each call)
    if (t < C) {
        float row[C];
        float m = -1e30f;
        #pragma unroll
        for (int j = 0; j < C; ++j) { row[j] = cm[t * C + j]; m = fmaxf(m, row[j]); }
        float s = 0.0f;
        #pragma unroll
        for (int j = 0; j < C; ++j) { row[j] = __expf(row[j] - m); s += row[j]; }
        float inv = 1.0f / s;
        #pragma unroll
        for (int j = 0; j < C; ++j) {
            float v = row[j] * inv;
            ws[t * C + j] = v;
            ws[361 + t * C + j] = __logf(v + EPS);
        }
    }
}

// 2 pixels per thread: xs[19][2] = 38 live floats -> fits VGPRs without
// AGPR spill (the 4-px version held 76 live, spilled, and pinned occupancy
// at 3 waves/SIMD). Loss uses unnormalized accumulation:
//   loss_pix = [sum_c ncm*e*(lpre + (x-m))] / [sum_c ncm*e] - log(s)
// which is identical to sum_c q*(lpre+log(pred)) up to the (negligible)
// EPS inside log(pred+EPS).
__global__ __launch_bounds__(256, 6) void emloss_main(
        const float* __restrict__ logits,
        const int* __restrict__ targets,
        const float* __restrict__ ws,
        float* __restrict__ pred,
        float* __restrict__ loss_acc) {
    __shared__ float s_ncm[C * C];
    __shared__ float s_lpre[C * C];
    __shared__ float s_red[4];
    for (int i = threadIdx.x; i < C * C; i += blockDim.x) {
        s_ncm[i]  = ws[i];
        s_lpre[i] = ws[361 + i];
    }
    __syncthreads();

    int g = blockIdx.x * blockDim.x + threadIdx.x;  // one group of 2 consecutive pixels
    int pbase = g * 2;                               // grid exactly covers NPIX
    int b = pbase >> 18;                             // / HW
    int r = pbase & (HW - 1);
    const float* lp = logits + (size_t)b * C * HW + r;
    float*       op = pred   + (size_t)b * C * HW + r;

    // 19 classes x 2 pixels, coalesced float2 per class (8 B/lane)
    float xs[C][2];
    #pragma unroll
    for (int c = 0; c < C; ++c) {
        float2 v = *(const float2*)(lp + (size_t)c * HW);
        xs[c][0] = v.x; xs[c][1] = v.y;
    }
    int2 tv = *(const int2*)(targets + pbase);
    int tt[2] = {tv.x, tv.y};

    float m[2] = {-1e30f, -1e30f};
    #pragma unroll
    for (int c = 0; c < C; ++c) {
        m[0] = fmaxf(m[0], xs[c][0]);
        m[1] = fmaxf(m[1], xs[c][1]);
    }

    // single fused pass: exp, softmax denom, loss numerator/denominator
    float s[2]     = {0.0f, 0.0f};
    float denom[2] = {0.0f, 0.0f};
    float acc[2]   = {0.0f, 0.0f};
    #pragma unroll
    for (int c = 0; c < C; ++c) {
        #pragma unroll
        for (int k = 0; k < 2; ++k) {
            float d = xs[c][k] - m[k];
            float e = __expf(d);
            s[k] += e;
            float num = s_ncm[c * C + tt[k]] * e;
            denom[k] += num;
            acc[k]   += num * (s_lpre[c * C + tt[k]] + d);
            xs[c][k] = e;   // keep unnormalized exp for pred store
        }
    }

    float inv0 = 1.0f / s[0], inv1 = 1.0f / s[1];
    #pragma unroll
    for (int c = 0; c < C; ++c) {
        float2 pv = make_float2(xs[c][0] * inv0, xs[c][1] * inv1);
        *(float2*)(op + (size_t)c * HW) = pv;
    }

    float lsum = (acc[0] / denom[0] - __logf(s[0]))
               + (acc[1] / denom[1] - __logf(s[1]));

    // wave-64 shuffle reduction -> LDS -> one atomic per block
    #pragma unroll
    for (int off = 32; off > 0; off >>= 1) lsum += __shfl_down(lsum, off);
    if ((threadIdx.x & 63) == 0) s_red[threadIdx.x >> 6] = lsum;
    __syncthreads();
    if (threadIdx.x == 0)
        atomicAdd(loss_acc, s_red[0] + s_red[1] + s_red[2] + s_red[3]);
}

__global__ void finalize_kernel(const float* __restrict__ acc, float* __restrict__ out) {
    out[0] = -acc[0] / (float)NPIX;
}

extern "C" void kernel_launch(void* const* d_in, const int* in_sizes, int n_in,
                              void* d_out, int out_size, void* d_ws, size_t ws_size,
                              hipStream_t stream) {
    const float* logits  = (const float*)d_in[0];
    const int*   targets = (const int*)d_in[1];
    const float* cm      = (const float*)d_in[2];
    float* out = (float*)d_out;
    float* ws  = (float*)d_ws;

    hipLaunchKernelGGL(ncm_kernel, dim3(1), dim3(64), 0, stream, cm, ws);

    int groups = NPIX / 2;            // 2097152
    int block = 256;
    int grid = groups / block;        // 8192
    hipLaunchKernelGGL(emloss_main, dim3(grid), dim3(block), 0, stream,
                       logits, targets, ws, out, ws + 768);

    hipLaunchKernelGGL(finalize_kernel, dim3(1), dim3(1), 0, stream,
                       ws + 768, out + NPRED);
}

// Round 2
// 514.888 us; speedup vs baseline: 1.1983x; 1.0285x over previous
//
#include <hip/hip_runtime.h>

#define EPS 1e-8f

constexpr int B = 16, C = 19, H = 512, W = 512;
constexpr int HW = H * W;               // 262144 = 2^18
constexpr int NPIX = B * HW;            // 4194304
constexpr long long NPRED = (long long)B * C * HW;  // 79691776

typedef float f32x4 __attribute__((ext_vector_type(4)));

// ws layout (floats): [0..360] ncm (row-major [c][t]), [361..721] log(ncm+eps), [768] loss accumulator

__global__ void ncm_kernel(const float* __restrict__ cm, float* __restrict__ ws) {
    int t = threadIdx.x;
    if (t == 0) ws[768] = 0.0f;  // zero the loss accumulator (ws is poisoned each call)
    if (t < C) {
        float row[C];
        float m = -1e30f;
        #pragma unroll
        for (int j = 0; j < C; ++j) { row[j] = cm[t * C + j]; m = fmaxf(m, row[j]); }
        float s = 0.0f;
        #pragma unroll
        for (int j = 0; j < C; ++j) { row[j] = __expf(row[j] - m); s += row[j]; }
        float inv = 1.0f / s;
        #pragma unroll
        for (int j = 0; j < C; ++j) {
            float v = row[j] * inv;
            ws[t * C + j] = v;
            ws[361 + t * C + j] = __logf(v + EPS);
        }
    }
}

// 4 pixels/thread, float4 (16 B/lane) non-temporal streaming.
// Live set: xs[19][4]=76 + accum/addr ~= 100 regs. __launch_bounds__(256,4)
// caps at 128 VGPRs -> fits with NO AGPR spill (the old 4-px version with
// bare __launch_bounds__(256) got 60 VGPR + spill, 3 waves/SIMD, 1.9 TB/s).
// Loss algebra (unnormalized accumulation, one log per pixel):
//   loss_pix = [sum_c ncm*e*(lpre + (x-m))] / [sum_c ncm*e] - log(s)
__global__ __launch_bounds__(256, 4) void emloss_main(
        const float* __restrict__ logits,
        const int* __restrict__ targets,
        const float* __restrict__ ws,
        float* __restrict__ pred,
        float* __restrict__ loss_acc) {
    __shared__ float s_ncm[C * C];
    __shared__ float s_lpre[C * C];
    __shared__ float s_red[4];
    for (int i = threadIdx.x; i < C * C; i += blockDim.x) {
        s_ncm[i]  = ws[i];
        s_lpre[i] = ws[361 + i];
    }
    __syncthreads();

    int g = blockIdx.x * blockDim.x + threadIdx.x;  // one group of 4 consecutive pixels
    int pbase = g * 4;                               // grid exactly covers NPIX
    int b = pbase >> 18;                             // / HW
    int r = pbase & (HW - 1);
    const float* lp = logits + (size_t)b * C * HW + r;
    float*       op = pred   + (size_t)b * C * HW + r;

    // 19 classes x 4 pixels, coalesced 16 B/lane non-temporal loads
    float xs[C][4];
    #pragma unroll
    for (int c = 0; c < C; ++c) {
        f32x4 v = __builtin_nontemporal_load((const f32x4*)(lp + (size_t)c * HW));
        xs[c][0] = v.x; xs[c][1] = v.y; xs[c][2] = v.z; xs[c][3] = v.w;
    }
    int4 tv = *(const int4*)(targets + pbase);
    int tt[4] = {tv.x, tv.y, tv.z, tv.w};

    float m[4] = {-1e30f, -1e30f, -1e30f, -1e30f};
    #pragma unroll
    for (int c = 0; c < C; ++c) {
        #pragma unroll
        for (int k = 0; k < 4; ++k) m[k] = fmaxf(m[k], xs[c][k]);
    }

    // single fused pass: exp, softmax denom, loss numerator/denominator
    float s[4]     = {0, 0, 0, 0};
    float denom[4] = {0, 0, 0, 0};
    float acc[4]   = {0, 0, 0, 0};
    #pragma unroll
    for (int c = 0; c < C; ++c) {
        #pragma unroll
        for (int k = 0; k < 4; ++k) {
            float d = xs[c][k] - m[k];
            float e = __expf(d);
            s[k] += e;
            float num = s_ncm[c * C + tt[k]] * e;
            denom[k] += num;
            acc[k]   += num * (s_lpre[c * C + tt[k]] + d);
            xs[c][k] = e;   // keep unnormalized exp for pred store
        }
    }

    float inv[4];
    #pragma unroll
    for (int k = 0; k < 4; ++k) inv[k] = 1.0f / s[k];
    #pragma unroll
    for (int c = 0; c < C; ++c) {
        f32x4 pv = {xs[c][0] * inv[0], xs[c][1] * inv[1],
                    xs[c][2] * inv[2], xs[c][3] * inv[3]};
        __builtin_nontemporal_store(pv, (f32x4*)(op + (size_t)c * HW));
    }

    float lsum = 0.0f;
    #pragma unroll
    for (int k = 0; k < 4; ++k) lsum += acc[k] / denom[k] - __logf(s[k]);

    // wave-64 shuffle reduction -> LDS -> one atomic per block
    #pragma unroll
    for (int off = 32; off > 0; off >>= 1) lsum += __shfl_down(lsum, off);
    if ((threadIdx.x & 63) == 0) s_red[threadIdx.x >> 6] = lsum;
    __syncthreads();
    if (threadIdx.x == 0)
        atomicAdd(loss_acc, s_red[0] + s_red[1] + s_red[2] + s_red[3]);
}

__global__ void finalize_kernel(const float* __restrict__ acc, float* __restrict__ out) {
    out[0] = -acc[0] / (float)NPIX;
}

extern "C" void kernel_launch(void* const* d_in, const int* in_sizes, int n_in,
                              void* d_out, int out_size, void* d_ws, size_t ws_size,
                              hipStream_t stream) {
    const float* logits  = (const float*)d_in[0];
    const int*   targets = (const int*)d_in[1];
    const float* cm      = (const float*)d_in[2];
    float* out = (float*)d_out;
    float* ws  = (float*)d_ws;

    hipLaunchKernelGGL(ncm_kernel, dim3(1), dim3(64), 0, stream, cm, ws);

    int groups = NPIX / 4;            // 1048576
    int block = 256;
    int grid = groups / block;        // 4096
    hipLaunchKernelGGL(emloss_main, dim3(grid), dim3(block), 0, stream,
                       logits, targets, ws, out, ws + 768);

    hipLaunchKernelGGL(finalize_kernel, dim3(1), dim3(1), 0, stream,
                       ws + 768, out + NPRED);
}